// Round 1
// baseline (256.196 us; speedup 1.0000x reference)
//
#include <hip/hip_runtime.h>
#include <hip/hip_bf16.h>
#include <math.h>

typedef __bf16 bf16_t;
typedef __attribute__((ext_vector_type(8))) __bf16 bf16x8;
typedef __attribute__((ext_vector_type(4))) __bf16 bf16x4;
typedef __attribute__((ext_vector_type(4))) float f32x4;

#define AS1C(p) ((const __attribute__((address_space(1))) void*)(p))
#define AS3(p)  ((__attribute__((address_space(3))) void*)(p))

// ---------------- convert f32 -> bf16, 4 elems/thread ----------------
__global__ __launch_bounds__(256) void k_cvt(const float* __restrict__ in,
                                             bf16_t* __restrict__ out, int n4) {
    int i = blockIdx.x * 256 + threadIdx.x;
    if (i < n4) {
        float4 v = reinterpret_cast<const float4*>(in)[i];
        bf16x4 o;
        o[0] = (bf16_t)v.x; o[1] = (bf16_t)v.y; o[2] = (bf16_t)v.z; o[3] = (bf16_t)v.w;
        reinterpret_cast<bf16x4*>(out)[i] = o;
    }
}

// ------------- transpose + convert: in (R x C f32) -> out (C x R bf16) -------------
__global__ __launch_bounds__(256) void k_tconv(const float* __restrict__ in,
                                               bf16_t* __restrict__ out, int R, int C) {
    __shared__ float tile[64][65];
    int r0 = blockIdx.y * 64, c0 = blockIdx.x * 64;
#pragma unroll
    for (int i = 0; i < 16; ++i) {
        int e = i * 256 + threadIdx.x;
        int r = e >> 6, c = e & 63;
        tile[r][c] = in[(size_t)(r0 + r) * C + c0 + c];
    }
    __syncthreads();
#pragma unroll
    for (int i = 0; i < 16; ++i) {
        int e = i * 256 + threadIdx.x;
        int c = e >> 6, r = e & 63;
        out[(size_t)(c0 + c) * R + r0 + r] = (bf16_t)tile[r][c];
    }
}

// ---------------- RoPE cos/sin tables: [1024][64] f32 each ----------------
__global__ __launch_bounds__(256) void k_tab(float* __restrict__ cosT,
                                             float* __restrict__ sinT) {
    int i = blockIdx.x * 256 + threadIdx.x;  // 65536 total
    int l = i >> 6, d = i & 63;
    int hh = l >> 5, ww = l & 31;            // H = W = 32
    float pos = (d < 32) ? (-1.0f + (2.0f / 31.0f) * (float)hh)
                         : (-1.0f + (2.0f / 31.0f) * (float)ww);
    int fi = (d & 31) >> 1;                  // linspace(1,128,16)[fi]
    float fb = (1.0f + (127.0f / 15.0f) * (float)fi) * 3.14159265358979323846f;
    float fr = pos * fb;
    cosT[i] = cosf(fr);
    sinT[i] = sinf(fr);
}

// ---------------- 128x128xK bf16 MFMA GEMM core (gemm_bt, 2-phase) ----------------
// A: M x K row-major bf16; Bt: N x K row-major bf16. 4 waves, wave (wr,wc) owns 64x64.
__device__ __forceinline__ void gemm_core(const bf16_t* __restrict__ A,
                                          const bf16_t* __restrict__ Bt,
                                          int K, int rowA0, int colB0,
                                          int w, int l, bf16_t* As, bf16_t* Bs,
                                          f32x4 acc[4][4]) {
    const int wr = w >> 1, wc = w & 1;
    for (int kt = 0; kt < K; kt += 64) {
#pragma unroll
        for (int i = 0; i < 4; ++i) {
            int rr = (i * 4 + w) * 8 + (l >> 3);   // tile row 0..127
            int ch = (l & 7) * 8;                  // elem offset in 64-wide k slice
            __builtin_amdgcn_global_load_lds(AS1C(A + (size_t)(rowA0 + rr) * K + kt + ch),
                                             AS3(As + (i * 4 + w) * 512), 16, 0, 0);
            __builtin_amdgcn_global_load_lds(AS1C(Bt + (size_t)(colB0 + rr) * K + kt + ch),
                                             AS3(Bs + (i * 4 + w) * 512), 16, 0, 0);
        }
        __syncthreads();   // drains vmcnt before barrier -> staging complete
#pragma unroll
        for (int kk = 0; kk < 2; ++kk) {
            bf16x8 af[4], bfr[4];
#pragma unroll
            for (int m = 0; m < 4; ++m)
                af[m] = *reinterpret_cast<const bf16x8*>(
                    As + (wr * 64 + m * 16 + (l & 15)) * 64 + kk * 32 + (l >> 4) * 8);
#pragma unroll
            for (int n = 0; n < 4; ++n)
                bfr[n] = *reinterpret_cast<const bf16x8*>(
                    Bs + (wc * 64 + n * 16 + (l & 15)) * 64 + kk * 32 + (l >> 4) * 8);
#pragma unroll
            for (int m = 0; m < 4; ++m)
#pragma unroll
                for (int n = 0; n < 4; ++n)
                    acc[m][n] = __builtin_amdgcn_mfma_f32_16x16x32_bf16(af[m], bfr[n],
                                                                        acc[m][n], 0, 0, 0);
        }
        __syncthreads();
    }
}

// ---------------- GEMM1: qkv = xb @ w_qkv, fused RoPE epilogue ----------------
// Writes qb, kb in (b,h,L,dh) bf16; vb in (b,h,dh,L) bf16 (transposed for PV).
__global__ __launch_bounds__(256) void k_gemm_qkv(const bf16_t* __restrict__ A,
                                                  const bf16_t* __restrict__ Bt,
                                                  const float* __restrict__ cosT,
                                                  const float* __restrict__ sinT,
                                                  bf16_t* __restrict__ qb,
                                                  bf16_t* __restrict__ kb,
                                                  bf16_t* __restrict__ vb) {
    __shared__ alignas(128) bf16_t As[128 * 64];
    __shared__ alignas(128) bf16_t Bs[128 * 64];
    const int tid = threadIdx.x, w = tid >> 6, l = tid & 63;
    const int rowA0 = blockIdx.y * 128, colB0 = blockIdx.x * 128;
    f32x4 acc[4][4] = {};
    gemm_core(A, Bt, 1024, rowA0, colB0, w, l, As, Bs, acc);
    const int wr = w >> 1, wc = w & 1;
    const int part = colB0 >> 10;   // 0=q 1=k 2=v, uniform per block (128 | 1024)
#pragma unroll
    for (int m = 0; m < 4; ++m) {
#pragma unroll
        for (int n = 0; n < 4; ++n) {
            const int c = colB0 + wc * 64 + n * 16 + (l & 15);
            const int head = (c & 1023) >> 6;
            const int d = c & 63;
            const int rbase = rowA0 + wr * 64 + m * 16 + (l >> 4) * 4;
            if (part == 2) {
#pragma unroll
                for (int r = 0; r < 4; ++r) {
                    int row = rbase + r;
                    int bb = row >> 10, ll = row & 1023;
                    vb[(((size_t)bb * 16 + head) * 64 + d) * 1024 + ll] = (bf16_t)acc[m][n][r];
                }
            } else {
                bf16_t* dst = (part == 0) ? qb : kb;
#pragma unroll
                for (int r = 0; r < 4; ++r) {
                    int row = rbase + r;
                    int bb = row >> 10, ll = row & 1023;
                    float v0 = acc[m][n][r];
                    float vp = __shfl_xor(v0, 1, 64);   // partner col d^1
                    float cs = cosT[ll * 64 + d];
                    float sn = sinT[ll * 64 + d];
                    // even d: x*cos - x[d+1]*sin ; odd d: x*cos + x[d-1]*sin
                    float res = (d & 1) ? fmaf(vp, sn, v0 * cs) : fmaf(-vp, sn, v0 * cs);
                    dst[(((size_t)bb * 16 + head) * 1024 + ll) * 64 + d] = (bf16_t)res;
                }
            }
        }
    }
}

// ---------------- GEMM2: out = ob @ w_proj, f32 epilogue ----------------
__global__ __launch_bounds__(256) void k_gemm_out(const bf16_t* __restrict__ A,
                                                  const bf16_t* __restrict__ Bt,
                                                  float* __restrict__ out) {
    __shared__ alignas(128) bf16_t As[128 * 64];
    __shared__ alignas(128) bf16_t Bs[128 * 64];
    const int tid = threadIdx.x, w = tid >> 6, l = tid & 63;
    const int rowA0 = blockIdx.y * 128, colB0 = blockIdx.x * 128;
    f32x4 acc[4][4] = {};
    gemm_core(A, Bt, 1024, rowA0, colB0, w, l, As, Bs, acc);
    const int wr = w >> 1, wc = w & 1;
#pragma unroll
    for (int m = 0; m < 4; ++m)
#pragma unroll
        for (int n = 0; n < 4; ++n) {
            int c = colB0 + wc * 64 + n * 16 + (l & 15);
            int rbase = rowA0 + wr * 64 + m * 16 + (l >> 4) * 4;
#pragma unroll
            for (int r = 0; r < 4; ++r)
                out[(size_t)(rbase + r) * 1024 + c] = acc[m][n][r];
        }
}

// ---------------- flash attention: one (b,h,64 q-rows) per block ----------------
// qb,kb: (b,h,L,dh) bf16 ; vb: (b,h,dh,L) bf16 ; ob: (b,L,h*dh) bf16
__global__ __launch_bounds__(256) void k_attn(const bf16_t* __restrict__ qb,
                                              const bf16_t* __restrict__ kb,
                                              const bf16_t* __restrict__ vb,
                                              bf16_t* __restrict__ ob) {
    __shared__ alignas(128) bf16_t Ks[64 * 64];   // [kv][dh]
    __shared__ alignas(128) bf16_t Vs[64 * 64];   // [dh][kv]
    __shared__ alignas(128) bf16_t Ps[4][16 * 64];
    const int tid = threadIdx.x, w = tid >> 6, l = tid & 63;
    const int bh = blockIdx.y, bi = bh >> 4, h = bh & 15;
    const int q0 = blockIdx.x * 64;
    const bf16_t* qbase = qb + (size_t)bh * 1024 * 64;
    const bf16_t* kbase = kb + (size_t)bh * 1024 * 64;
    const bf16_t* vbase = vb + (size_t)bh * 64 * 1024;

    // hoist Q fragments: wave's 16 rows
    bf16x8 qf[2];
    {
        int qrow = q0 + w * 16 + (l & 15);
        qf[0] = *reinterpret_cast<const bf16x8*>(qbase + (size_t)qrow * 64 + (l >> 4) * 8);
        qf[1] = *reinterpret_cast<const bf16x8*>(qbase + (size_t)qrow * 64 + 32 + (l >> 4) * 8);
    }
    float m_run[4] = {-1e30f, -1e30f, -1e30f, -1e30f};
    float l_run[4] = {0.f, 0.f, 0.f, 0.f};
    f32x4 o_acc[4] = {};
    bf16_t* Pw = &Ps[w][0];

    for (int t = 0; t < 16; ++t) {
        int kv0 = t * 64;
#pragma unroll
        for (int i = 0; i < 2; ++i) {
            // K tile: contiguous 8KB copy
            __builtin_amdgcn_global_load_lds(
                AS1C(kbase + (size_t)kv0 * 64 + (i * 4 + w) * 512 + l * 8),
                AS3(Ks + (i * 4 + w) * 512), 16, 0, 0);
            // V tile: 64 dh-rows of 128B from (dh,L) layout
            int rr = (i * 4 + w) * 8 + (l >> 3);
            __builtin_amdgcn_global_load_lds(
                AS1C(vbase + (size_t)rr * 1024 + kv0 + (l & 7) * 8),
                AS3(Vs + (i * 4 + w) * 512), 16, 0, 0);
        }
        __syncthreads();

        // S = Q @ K^T  (16 q-rows x 64 kv)
        f32x4 sacc[4] = {};
#pragma unroll
        for (int kk = 0; kk < 2; ++kk) {
            bf16x8 kf[4];
#pragma unroll
            for (int n = 0; n < 4; ++n)
                kf[n] = *reinterpret_cast<const bf16x8*>(
                    Ks + (n * 16 + (l & 15)) * 64 + kk * 32 + (l >> 4) * 8);
#pragma unroll
            for (int n = 0; n < 4; ++n)
                sacc[n] = __builtin_amdgcn_mfma_f32_16x16x32_bf16(qf[kk], kf[n], sacc[n], 0, 0, 0);
        }

        // online softmax (rows replicated across the 16-lane group)
        const float sc = 1.0f / 64.0f;
#pragma unroll
        for (int r = 0; r < 4; ++r) {
            float s0 = sacc[0][r] * sc, s1 = sacc[1][r] * sc;
            float s2 = sacc[2][r] * sc, s3 = sacc[3][r] * sc;
            float tm = fmaxf(fmaxf(s0, s1), fmaxf(s2, s3));
            tm = fmaxf(tm, __shfl_xor(tm, 1, 64));
            tm = fmaxf(tm, __shfl_xor(tm, 2, 64));
            tm = fmaxf(tm, __shfl_xor(tm, 4, 64));
            tm = fmaxf(tm, __shfl_xor(tm, 8, 64));
            float mn = fmaxf(m_run[r], tm);
            float corr = __expf(m_run[r] - mn);
            float p0 = __expf(s0 - mn), p1 = __expf(s1 - mn);
            float p2 = __expf(s2 - mn), p3 = __expf(s3 - mn);
            l_run[r] = l_run[r] * corr + (p0 + p1 + p2 + p3);  // lane-partial sum
            m_run[r] = mn;
#pragma unroll
            for (int n = 0; n < 4; ++n) o_acc[n][r] *= corr;
            int prow = (l >> 4) * 4 + r;
            Pw[prow * 64 +  0 + (l & 15)] = (bf16_t)p0;
            Pw[prow * 64 + 16 + (l & 15)] = (bf16_t)p1;
            Pw[prow * 64 + 32 + (l & 15)] = (bf16_t)p2;
            Pw[prow * 64 + 48 + (l & 15)] = (bf16_t)p3;
        }
        __syncthreads();

        // O += P @ V   (A = P[16 x 64kv], B = V^T stored as Vs[dh][kv])
#pragma unroll
        for (int kk = 0; kk < 2; ++kk) {
            bf16x8 pf = *reinterpret_cast<const bf16x8*>(
                Pw + (l & 15) * 64 + kk * 32 + (l >> 4) * 8);
#pragma unroll
            for (int n = 0; n < 4; ++n) {
                bf16x8 vf = *reinterpret_cast<const bf16x8*>(
                    Vs + (n * 16 + (l & 15)) * 64 + kk * 32 + (l >> 4) * 8);
                o_acc[n] = __builtin_amdgcn_mfma_f32_16x16x32_bf16(pf, vf, o_acc[n], 0, 0, 0);
            }
        }
        __syncthreads();
    }

    // epilogue: full row-sum, normalize, write (b, l, h*64+d)
#pragma unroll
    for (int r = 0; r < 4; ++r) {
        float lsum = l_run[r];
        lsum += __shfl_xor(lsum, 1, 64);
        lsum += __shfl_xor(lsum, 2, 64);
        lsum += __shfl_xor(lsum, 4, 64);
        lsum += __shfl_xor(lsum, 8, 64);
        float inv = 1.0f / lsum;
        int row = q0 + w * 16 + (l >> 4) * 4 + r;
#pragma unroll
        for (int n = 0; n < 4; ++n)
            ob[((size_t)bi * 1024 + row) * 1024 + h * 64 + n * 16 + (l & 15)] =
                (bf16_t)(o_acc[n][r] * inv);
    }
}

extern "C" void kernel_launch(void* const* d_in, const int* in_sizes, int n_in,
                              void* d_out, int out_size, void* d_ws, size_t ws_size,
                              hipStream_t stream) {
    (void)in_sizes; (void)n_in; (void)out_size; (void)ws_size;
    const float* x     = (const float*)d_in[0];
    const float* wqkv  = (const float*)d_in[1];
    const float* wproj = (const float*)d_in[2];
    char* ws = (char*)d_ws;

    bf16_t* xb  = (bf16_t*)(ws);                       // 8192x1024      16,777,216 B
    bf16_t* wqT = (bf16_t*)(ws + 16777216ull);          // 3072x1024       6,291,456 B
    bf16_t* wpT = (bf16_t*)(ws + 23068672ull);          // 1024x1024       2,097,152 B
    bf16_t* qb  = (bf16_t*)(ws + 25165824ull);          // (b,h,L,dh)     16,777,216 B
    bf16_t* kb  = (bf16_t*)(ws + 41943040ull);          // (b,h,L,dh)     16,777,216 B
    bf16_t* vb  = (bf16_t*)(ws + 58720256ull);          // (b,h,dh,L)     16,777,216 B
    bf16_t* ob  = (bf16_t*)(ws + 75497472ull);          // (b,L,1024)     16,777,216 B
    float*  cosT = (float*)(ws + 92274688ull);          //                   262,144 B
    float*  sinT = (float*)(ws + 92536832ull);          //                   262,144 B

    k_cvt<<<8192, 256, 0, stream>>>(x, xb, 2097152);
    k_tconv<<<dim3(48, 16), 256, 0, stream>>>(wqkv, wqT, 1024, 3072);
    k_tconv<<<dim3(16, 16), 256, 0, stream>>>(wproj, wpT, 1024, 1024);
    k_tab<<<256, 256, 0, stream>>>(cosT, sinT);
    k_gemm_qkv<<<dim3(24, 64), 256, 0, stream>>>(xb, wqT, cosT, sinT, qb, kb, vb);
    k_attn<<<dim3(16, 128), 256, 0, stream>>>(qb, kb, vb, ob);
    k_gemm_out<<<dim3(8, 64), 256, 0, stream>>>(ob, wpT, (float*)d_out);
}

// Round 2
// 227.684 us; speedup vs baseline: 1.1252x; 1.1252x over previous
//
#include <hip/hip_runtime.h>
#include <hip/hip_bf16.h>
#include <math.h>

typedef __bf16 bf16_t;
typedef __attribute__((ext_vector_type(8))) __bf16 bf16x8;
typedef __attribute__((ext_vector_type(4))) __bf16 bf16x4;
typedef __attribute__((ext_vector_type(4))) float f32x4;

#define AS1C(p) ((const __attribute__((address_space(1))) void*)(p))
#define AS3(p)  ((__attribute__((address_space(3))) void*)(p))

__device__ __forceinline__ float fast_exp2(float x) { return __builtin_amdgcn_exp2f(x); }

// ---------------- convert f32 -> bf16, 4 elems/thread ----------------
__global__ __launch_bounds__(256) void k_cvt(const float* __restrict__ in,
                                             bf16_t* __restrict__ out, int n4) {
    int i = blockIdx.x * 256 + threadIdx.x;
    if (i < n4) {
        float4 v = reinterpret_cast<const float4*>(in)[i];
        bf16x4 o;
        o[0] = (bf16_t)v.x; o[1] = (bf16_t)v.y; o[2] = (bf16_t)v.z; o[3] = (bf16_t)v.w;
        reinterpret_cast<bf16x4*>(out)[i] = o;
    }
}

// ------------- transpose + convert: in (R x C f32) -> out (C x R bf16) -------------
__global__ __launch_bounds__(256) void k_tconv(const float* __restrict__ in,
                                               bf16_t* __restrict__ out, int R, int C) {
    __shared__ float tile[64][65];
    int r0 = blockIdx.y * 64, c0 = blockIdx.x * 64;
#pragma unroll
    for (int i = 0; i < 16; ++i) {
        int e = i * 256 + threadIdx.x;
        int r = e >> 6, c = e & 63;
        tile[r][c] = in[(size_t)(r0 + r) * C + c0 + c];
    }
    __syncthreads();
#pragma unroll
    for (int i = 0; i < 16; ++i) {
        int e = i * 256 + threadIdx.x;
        int c = e >> 6, r = e & 63;
        out[(size_t)(c0 + c) * R + r0 + r] = (bf16_t)tile[r][c];
    }
}

// ---------------- RoPE cos/sin tables: [1024][64] f32 each ----------------
__global__ __launch_bounds__(256) void k_tab(float* __restrict__ cosT,
                                             float* __restrict__ sinT) {
    int i = blockIdx.x * 256 + threadIdx.x;  // 65536 total
    int l = i >> 6, d = i & 63;
    int hh = l >> 5, ww = l & 31;            // H = W = 32
    float pos = (d < 32) ? (-1.0f + (2.0f / 31.0f) * (float)hh)
                         : (-1.0f + (2.0f / 31.0f) * (float)ww);
    int fi = (d & 31) >> 1;                  // linspace(1,128,16)[fi]
    float fb = (1.0f + (127.0f / 15.0f) * (float)fi) * 3.14159265358979323846f;
    float fr = pos * fb;
    cosT[i] = cosf(fr);
    sinT[i] = sinf(fr);
}

// ---------------- 128x128xK bf16 MFMA GEMM core (gemm_bt, 2-phase) ----------------
__device__ __forceinline__ void gemm_core(const bf16_t* __restrict__ A,
                                          const bf16_t* __restrict__ Bt,
                                          int K, int rowA0, int colB0,
                                          int w, int l, bf16_t* As, bf16_t* Bs,
                                          f32x4 acc[4][4]) {
    const int wr = w >> 1, wc = w & 1;
    for (int kt = 0; kt < K; kt += 64) {
#pragma unroll
        for (int i = 0; i < 4; ++i) {
            int rr = (i * 4 + w) * 8 + (l >> 3);
            int ch = (l & 7) * 8;
            __builtin_amdgcn_global_load_lds(AS1C(A + (size_t)(rowA0 + rr) * K + kt + ch),
                                             AS3(As + (i * 4 + w) * 512), 16, 0, 0);
            __builtin_amdgcn_global_load_lds(AS1C(Bt + (size_t)(colB0 + rr) * K + kt + ch),
                                             AS3(Bs + (i * 4 + w) * 512), 16, 0, 0);
        }
        __syncthreads();
#pragma unroll
        for (int kk = 0; kk < 2; ++kk) {
            bf16x8 af[4], bfr[4];
#pragma unroll
            for (int m = 0; m < 4; ++m)
                af[m] = *reinterpret_cast<const bf16x8*>(
                    As + (wr * 64 + m * 16 + (l & 15)) * 64 + kk * 32 + (l >> 4) * 8);
#pragma unroll
            for (int n = 0; n < 4; ++n)
                bfr[n] = *reinterpret_cast<const bf16x8*>(
                    Bs + (wc * 64 + n * 16 + (l & 15)) * 64 + kk * 32 + (l >> 4) * 8);
#pragma unroll
            for (int m = 0; m < 4; ++m)
#pragma unroll
                for (int n = 0; n < 4; ++n)
                    acc[m][n] = __builtin_amdgcn_mfma_f32_16x16x32_bf16(af[m], bfr[n],
                                                                        acc[m][n], 0, 0, 0);
        }
        __syncthreads();
    }
}

// ---------------- GEMM1: qkv = xb @ w_qkv, fused RoPE epilogue ----------------
__global__ __launch_bounds__(256) void k_gemm_qkv(const bf16_t* __restrict__ A,
                                                  const bf16_t* __restrict__ Bt,
                                                  const float* __restrict__ cosT,
                                                  const float* __restrict__ sinT,
                                                  bf16_t* __restrict__ qb,
                                                  bf16_t* __restrict__ kb,
                                                  bf16_t* __restrict__ vb) {
    __shared__ alignas(128) bf16_t As[128 * 64];
    __shared__ alignas(128) bf16_t Bs[128 * 64];
    const int tid = threadIdx.x, w = tid >> 6, l = tid & 63;
    const int rowA0 = blockIdx.y * 128, colB0 = blockIdx.x * 128;
    f32x4 acc[4][4] = {};
    gemm_core(A, Bt, 1024, rowA0, colB0, w, l, As, Bs, acc);
    const int wr = w >> 1, wc = w & 1;
    const int part = colB0 >> 10;
#pragma unroll
    for (int m = 0; m < 4; ++m) {
#pragma unroll
        for (int n = 0; n < 4; ++n) {
            const int c = colB0 + wc * 64 + n * 16 + (l & 15);
            const int head = (c & 1023) >> 6;
            const int d = c & 63;
            const int rbase = rowA0 + wr * 64 + m * 16 + (l >> 4) * 4;
            if (part == 2) {
#pragma unroll
                for (int r = 0; r < 4; ++r) {
                    int row = rbase + r;
                    int bb = row >> 10, ll = row & 1023;
                    vb[(((size_t)bb * 16 + head) * 64 + d) * 1024 + ll] = (bf16_t)acc[m][n][r];
                }
            } else {
                bf16_t* dst = (part == 0) ? qb : kb;
#pragma unroll
                for (int r = 0; r < 4; ++r) {
                    int row = rbase + r;
                    int bb = row >> 10, ll = row & 1023;
                    float v0 = acc[m][n][r];
                    float vp = __shfl_xor(v0, 1, 64);
                    float cs = cosT[ll * 64 + d];
                    float sn = sinT[ll * 64 + d];
                    float res = (d & 1) ? fmaf(vp, sn, v0 * cs) : fmaf(-vp, sn, v0 * cs);
                    dst[(((size_t)bb * 16 + head) * 1024 + ll) * 64 + d] = (bf16_t)res;
                }
            }
        }
    }
}

// ---------------- GEMM2: out = ob @ w_proj, f32 epilogue ----------------
__global__ __launch_bounds__(256) void k_gemm_out(const bf16_t* __restrict__ A,
                                                  const bf16_t* __restrict__ Bt,
                                                  float* __restrict__ out) {
    __shared__ alignas(128) bf16_t As[128 * 64];
    __shared__ alignas(128) bf16_t Bs[128 * 64];
    const int tid = threadIdx.x, w = tid >> 6, l = tid & 63;
    const int rowA0 = blockIdx.y * 128, colB0 = blockIdx.x * 128;
    f32x4 acc[4][4] = {};
    gemm_core(A, Bt, 1024, rowA0, colB0, w, l, As, Bs, acc);
    const int wr = w >> 1, wc = w & 1;
#pragma unroll
    for (int m = 0; m < 4; ++m)
#pragma unroll
        for (int n = 0; n < 4; ++n) {
            int c = colB0 + wc * 64 + n * 16 + (l & 15);
            int rbase = rowA0 + wr * 64 + m * 16 + (l >> 4) * 4;
#pragma unroll
            for (int r = 0; r < 4; ++r)
                out[(size_t)(rbase + r) * 1024 + c] = acc[m][n][r];
        }
}

// ---------------- flash attention v2 ----------------
// Block: 128 q-rows of one (b,h); 4 waves x 32 rows (two 16-row sub-blocks m=0,1).
// K/V double-buffered + XOR-swizzled LDS; P per-wave padded LDS; exp2 softmax
// with defer-max; 1 barrier per KV tile; XCD-swizzled block id.
__global__ __launch_bounds__(256, 3) void k_attn(const bf16_t* __restrict__ qb,
                                                 const bf16_t* __restrict__ kb,
                                                 const bf16_t* __restrict__ vb,
                                                 bf16_t* __restrict__ ob) {
    __shared__ alignas(128) bf16_t Ks[2][64 * 64];
    __shared__ alignas(128) bf16_t Vs[2][64 * 64];
    __shared__ alignas(128) bf16_t Ps[4][32 * 72];
    const int tid = threadIdx.x, w = tid >> 6, l = tid & 63;
    const int bid = blockIdx.x;                       // 0..1023
    const int bs = (bid & 7) * 128 + (bid >> 3);      // XCD-aware bijective swizzle
    const int bh = bs >> 3, bi = bh >> 4, h = bh & 15;
    const int q0 = (bs & 7) * 128;
    const bf16_t* qbase = qb + (size_t)bh * 1024 * 64;
    const bf16_t* kbase = kb + (size_t)bh * 1024 * 64;
    const bf16_t* vbase = vb + (size_t)bh * 64 * 1024;
    bf16_t* Pw = &Ps[w][0];

    // Q fragments for both 16-row sub-blocks
    bf16x8 qf[2][2];
#pragma unroll
    for (int m = 0; m < 2; ++m) {
        int qrow = q0 + m * 64 + w * 16 + (l & 15);
#pragma unroll
        for (int kk = 0; kk < 2; ++kk)
            qf[m][kk] = *reinterpret_cast<const bf16x8*>(
                qbase + (size_t)qrow * 64 + kk * 32 + (l >> 4) * 8);
    }

    float m_run[2][4], l_run[2][4];
    f32x4 o_acc[2][4] = {};
#pragma unroll
    for (int m = 0; m < 2; ++m)
#pragma unroll
        for (int r = 0; r < 4; ++r) { m_run[m][r] = -1e30f; l_run[m][r] = 0.f; }

    // staging: linear LDS dest, inverse-swizzled global source (rule #21)
    const int srow = l >> 3;                 // row within 8-row chunk; srow == row&7
    const int sc = 8 * ((l & 7) ^ srow);     // swizzled elem col within 64-wide slice
#define STAGE(buf, kv0)                                                                   \
    {                                                                                     \
        _Pragma("unroll")                                                                 \
        for (int i = 0; i < 2; ++i) {                                                     \
            int rr = (i * 4 + w) * 8 + srow;                                              \
            __builtin_amdgcn_global_load_lds(AS1C(kbase + (size_t)((kv0) + rr) * 64 + sc),\
                                             AS3(&Ks[buf][(i * 4 + w) * 512]), 16, 0, 0); \
            __builtin_amdgcn_global_load_lds(AS1C(vbase + (size_t)rr * 1024 + (kv0) + sc),\
                                             AS3(&Vs[buf][(i * 4 + w) * 512]), 16, 0, 0); \
        }                                                                                 \
    }

    STAGE(0, 0);
    __syncthreads();

    const float SCL = 1.4426950408889634f / 64.0f;   // softmax scale in log2 domain
    int cur = 0;
    for (int t = 0; t < 16; ++t) {
        if (t < 15) STAGE(cur ^ 1, (t + 1) * 64);

        // ---- S^(m) = Q^(m) @ K^T, shared K fragments ----
        f32x4 sacc[2][4] = {};
#pragma unroll
        for (int kk = 0; kk < 2; ++kk)
#pragma unroll
            for (int n = 0; n < 4; ++n) {
                int rr = n * 16 + (l & 15);
                int ec = (kk * 32 + (l >> 4) * 8) ^ ((l & 7) << 3);
                bf16x8 kfr = *reinterpret_cast<const bf16x8*>(&Ks[cur][rr * 64 + ec]);
                sacc[0][n] = __builtin_amdgcn_mfma_f32_16x16x32_bf16(qf[0][kk], kfr, sacc[0][n], 0, 0, 0);
                sacc[1][n] = __builtin_amdgcn_mfma_f32_16x16x32_bf16(qf[1][kk], kfr, sacc[1][n], 0, 0, 0);
            }

        // ---- online softmax (log2 domain, defer-max THR=8) ----
#pragma unroll
        for (int m = 0; m < 2; ++m)
#pragma unroll
            for (int r = 0; r < 4; ++r) {
                float s0 = sacc[m][0][r] * SCL, s1 = sacc[m][1][r] * SCL;
                float s2 = sacc[m][2][r] * SCL, s3 = sacc[m][3][r] * SCL;
                float mx = fmaxf(fmaxf(s0, s1), fmaxf(s2, s3));
                mx = fmaxf(mx, __shfl_xor(mx, 1, 64));
                mx = fmaxf(mx, __shfl_xor(mx, 2, 64));
                mx = fmaxf(mx, __shfl_xor(mx, 4, 64));
                mx = fmaxf(mx, __shfl_xor(mx, 8, 64));
                float mo = m_run[m][r];
                if (mx > mo + 8.0f) {
                    float corr = fast_exp2(mo - mx);
                    l_run[m][r] *= corr;
                    o_acc[m][0][r] *= corr; o_acc[m][1][r] *= corr;
                    o_acc[m][2][r] *= corr; o_acc[m][3][r] *= corr;
                    m_run[m][r] = mx; mo = mx;
                }
                float p0 = fast_exp2(s0 - mo), p1 = fast_exp2(s1 - mo);
                float p2 = fast_exp2(s2 - mo), p3 = fast_exp2(s3 - mo);
                l_run[m][r] += (p0 + p1) + (p2 + p3);
                int pr = (m * 16 + (l >> 4) * 4 + r) * 72 + (l & 15);
                Pw[pr] = (bf16_t)p0; Pw[pr + 16] = (bf16_t)p1;
                Pw[pr + 32] = (bf16_t)p2; Pw[pr + 48] = (bf16_t)p3;
            }

        // ---- O^(m) += P^(m) @ V, shared V fragments (in-order DS: no barrier for P) ----
#pragma unroll
        for (int kk = 0; kk < 2; ++kk) {
            bf16x8 pf0 = *reinterpret_cast<const bf16x8*>(
                Pw + ((l & 15)) * 72 + kk * 32 + (l >> 4) * 8);
            bf16x8 pf1 = *reinterpret_cast<const bf16x8*>(
                Pw + (16 + (l & 15)) * 72 + kk * 32 + (l >> 4) * 8);
#pragma unroll
            for (int n = 0; n < 4; ++n) {
                int rr = n * 16 + (l & 15);
                int ec = (kk * 32 + (l >> 4) * 8) ^ ((l & 7) << 3);
                bf16x8 vfr = *reinterpret_cast<const bf16x8*>(&Vs[cur][rr * 64 + ec]);
                o_acc[0][n] = __builtin_amdgcn_mfma_f32_16x16x32_bf16(pf0, vfr, o_acc[0][n], 0, 0, 0);
                o_acc[1][n] = __builtin_amdgcn_mfma_f32_16x16x32_bf16(pf1, vfr, o_acc[1][n], 0, 0, 0);
            }
        }
        __syncthreads();
        cur ^= 1;
    }

    // ---- epilogue ----
#pragma unroll
    for (int m = 0; m < 2; ++m)
#pragma unroll
        for (int r = 0; r < 4; ++r) {
            float ls = l_run[m][r];
            ls += __shfl_xor(ls, 1, 64);
            ls += __shfl_xor(ls, 2, 64);
            ls += __shfl_xor(ls, 4, 64);
            ls += __shfl_xor(ls, 8, 64);
            float inv = 1.0f / ls;
            int row = q0 + m * 64 + w * 16 + (l >> 4) * 4 + r;
#pragma unroll
            for (int n = 0; n < 4; ++n)
                ob[((size_t)bi * 1024 + row) * 1024 + h * 64 + n * 16 + (l & 15)] =
                    (bf16_t)(o_acc[m][n][r] * inv);
        }
#undef STAGE
}

extern "C" void kernel_launch(void* const* d_in, const int* in_sizes, int n_in,
                              void* d_out, int out_size, void* d_ws, size_t ws_size,
                              hipStream_t stream) {
    (void)in_sizes; (void)n_in; (void)out_size; (void)ws_size;
    const float* x     = (const float*)d_in[0];
    const float* wqkv  = (const float*)d_in[1];
    const float* wproj = (const float*)d_in[2];
    char* ws = (char*)d_ws;

    bf16_t* xb  = (bf16_t*)(ws);
    bf16_t* wqT = (bf16_t*)(ws + 16777216ull);
    bf16_t* wpT = (bf16_t*)(ws + 23068672ull);
    bf16_t* qb  = (bf16_t*)(ws + 25165824ull);
    bf16_t* kb  = (bf16_t*)(ws + 41943040ull);
    bf16_t* vb  = (bf16_t*)(ws + 58720256ull);
    bf16_t* ob  = (bf16_t*)(ws + 75497472ull);
    float*  cosT = (float*)(ws + 92274688ull);
    float*  sinT = (float*)(ws + 92536832ull);

    k_cvt<<<8192, 256, 0, stream>>>(x, xb, 2097152);
    k_tconv<<<dim3(48, 16), 256, 0, stream>>>(wqkv, wqT, 1024, 3072);
    k_tconv<<<dim3(16, 16), 256, 0, stream>>>(wproj, wpT, 1024, 1024);
    k_tab<<<256, 256, 0, stream>>>(cosT, sinT);
    k_gemm_qkv<<<dim3(24, 64), 256, 0, stream>>>(xb, wqT, cosT, sinT, qb, kb, vb);
    k_attn<<<1024, 256, 0, stream>>>(qb, kb, vb, ob);
    k_gemm_out<<<dim3(8, 64), 256, 0, stream>>>(ob, wpT, (float*)d_out);
}

// Round 3
// 188.797 us; speedup vs baseline: 1.3570x; 1.2060x over previous
//
#include <hip/hip_runtime.h>
#include <hip/hip_bf16.h>
#include <math.h>

typedef __bf16 bf16_t;
typedef __attribute__((ext_vector_type(8))) __bf16 bf16x8;
typedef __attribute__((ext_vector_type(4))) __bf16 bf16x4;
typedef __attribute__((ext_vector_type(4))) short s16x4;
typedef __attribute__((ext_vector_type(4))) float f32x4;

#define AS1C(p) ((const __attribute__((address_space(1))) void*)(p))
#define AS3(p)  ((__attribute__((address_space(3))) void*)(p))

__device__ __forceinline__ float fast_exp2(float x) { return __builtin_amdgcn_exp2f(x); }

// ---------------- convert f32 -> bf16, 4 elems/thread ----------------
__global__ __launch_bounds__(256) void k_cvt(const float* __restrict__ in,
                                             bf16_t* __restrict__ out, int n4) {
    int i = blockIdx.x * 256 + threadIdx.x;
    if (i < n4) {
        float4 v = reinterpret_cast<const float4*>(in)[i];
        bf16x4 o;
        o[0] = (bf16_t)v.x; o[1] = (bf16_t)v.y; o[2] = (bf16_t)v.z; o[3] = (bf16_t)v.w;
        reinterpret_cast<bf16x4*>(out)[i] = o;
    }
}

// ------------- transpose + convert: in (R x C f32) -> out (C x R bf16) -------------
__global__ __launch_bounds__(256) void k_tconv(const float* __restrict__ in,
                                               bf16_t* __restrict__ out, int R, int C) {
    __shared__ float tile[64][65];
    int r0 = blockIdx.y * 64, c0 = blockIdx.x * 64;
#pragma unroll
    for (int i = 0; i < 16; ++i) {
        int e = i * 256 + threadIdx.x;
        int r = e >> 6, c = e & 63;
        tile[r][c] = in[(size_t)(r0 + r) * C + c0 + c];
    }
    __syncthreads();
#pragma unroll
    for (int i = 0; i < 16; ++i) {
        int e = i * 256 + threadIdx.x;
        int c = e >> 6, r = e & 63;
        out[(size_t)(c0 + c) * R + r0 + r] = (bf16_t)tile[r][c];
    }
}

// ---------------- RoPE cos/sin tables: [1024][64] f32 each ----------------
__global__ __launch_bounds__(256) void k_tab(float* __restrict__ cosT,
                                             float* __restrict__ sinT) {
    int i = blockIdx.x * 256 + threadIdx.x;  // 65536 total
    int l = i >> 6, d = i & 63;
    int hh = l >> 5, ww = l & 31;            // H = W = 32
    float pos = (d < 32) ? (-1.0f + (2.0f / 31.0f) * (float)hh)
                         : (-1.0f + (2.0f / 31.0f) * (float)ww);
    int fi = (d & 31) >> 1;                  // linspace(1,128,16)[fi]
    float fb = (1.0f + (127.0f / 15.0f) * (float)fi) * 3.14159265358979323846f;
    float fr = pos * fb;
    cosT[i] = cosf(fr);
    sinT[i] = sinf(fr);
}

// ---------------- 128x128xK bf16 MFMA GEMM core (gemm_bt, 2-phase) ----------------
__device__ __forceinline__ void gemm_core(const bf16_t* __restrict__ A,
                                          const bf16_t* __restrict__ Bt,
                                          int K, int rowA0, int colB0,
                                          int w, int l, bf16_t* As, bf16_t* Bs,
                                          f32x4 acc[4][4]) {
    const int wr = w >> 1, wc = w & 1;
    for (int kt = 0; kt < K; kt += 64) {
#pragma unroll
        for (int i = 0; i < 4; ++i) {
            int rr = (i * 4 + w) * 8 + (l >> 3);
            int ch = (l & 7) * 8;
            __builtin_amdgcn_global_load_lds(AS1C(A + (size_t)(rowA0 + rr) * K + kt + ch),
                                             AS3(As + (i * 4 + w) * 512), 16, 0, 0);
            __builtin_amdgcn_global_load_lds(AS1C(Bt + (size_t)(colB0 + rr) * K + kt + ch),
                                             AS3(Bs + (i * 4 + w) * 512), 16, 0, 0);
        }
        __syncthreads();
#pragma unroll
        for (int kk = 0; kk < 2; ++kk) {
            bf16x8 af[4], bfr[4];
#pragma unroll
            for (int m = 0; m < 4; ++m)
                af[m] = *reinterpret_cast<const bf16x8*>(
                    As + (wr * 64 + m * 16 + (l & 15)) * 64 + kk * 32 + (l >> 4) * 8);
#pragma unroll
            for (int n = 0; n < 4; ++n)
                bfr[n] = *reinterpret_cast<const bf16x8*>(
                    Bs + (wc * 64 + n * 16 + (l & 15)) * 64 + kk * 32 + (l >> 4) * 8);
#pragma unroll
            for (int m = 0; m < 4; ++m)
#pragma unroll
                for (int n = 0; n < 4; ++n)
                    acc[m][n] = __builtin_amdgcn_mfma_f32_16x16x32_bf16(af[m], bfr[n],
                                                                        acc[m][n], 0, 0, 0);
        }
        __syncthreads();
    }
}

// ---------------- GEMM1: qkv = xb @ w_qkv, fused RoPE epilogue ----------------
__global__ __launch_bounds__(256) void k_gemm_qkv(const bf16_t* __restrict__ A,
                                                  const bf16_t* __restrict__ Bt,
                                                  const float* __restrict__ cosT,
                                                  const float* __restrict__ sinT,
                                                  bf16_t* __restrict__ qb,
                                                  bf16_t* __restrict__ kb,
                                                  bf16_t* __restrict__ vb) {
    __shared__ alignas(128) bf16_t As[128 * 64];
    __shared__ alignas(128) bf16_t Bs[128 * 64];
    const int tid = threadIdx.x, w = tid >> 6, l = tid & 63;
    const int rowA0 = blockIdx.y * 128, colB0 = blockIdx.x * 128;
    f32x4 acc[4][4] = {};
    gemm_core(A, Bt, 1024, rowA0, colB0, w, l, As, Bs, acc);
    const int wr = w >> 1, wc = w & 1;
    const int part = colB0 >> 10;
#pragma unroll
    for (int m = 0; m < 4; ++m) {
#pragma unroll
        for (int n = 0; n < 4; ++n) {
            const int c = colB0 + wc * 64 + n * 16 + (l & 15);
            const int head = (c & 1023) >> 6;
            const int d = c & 63;
            const int rbase = rowA0 + wr * 64 + m * 16 + (l >> 4) * 4;
            if (part == 2) {
#pragma unroll
                for (int r = 0; r < 4; ++r) {
                    int row = rbase + r;
                    int bb = row >> 10, ll = row & 1023;
                    vb[(((size_t)bb * 16 + head) * 64 + d) * 1024 + ll] = (bf16_t)acc[m][n][r];
                }
            } else {
                bf16_t* dst = (part == 0) ? qb : kb;
#pragma unroll
                for (int r = 0; r < 4; ++r) {
                    int row = rbase + r;
                    int bb = row >> 10, ll = row & 1023;
                    float v0 = acc[m][n][r];
                    float vp = __shfl_xor(v0, 1, 64);
                    float cs = cosT[ll * 64 + d];
                    float sn = sinT[ll * 64 + d];
                    float res = (d & 1) ? fmaf(vp, sn, v0 * cs) : fmaf(-vp, sn, v0 * cs);
                    dst[(((size_t)bb * 16 + head) * 1024 + ll) * 64 + d] = (bf16_t)res;
                }
            }
        }
    }
}

// ---------------- GEMM2: out = ob @ w_proj, f32 epilogue ----------------
__global__ __launch_bounds__(256) void k_gemm_out(const bf16_t* __restrict__ A,
                                                  const bf16_t* __restrict__ Bt,
                                                  float* __restrict__ out) {
    __shared__ alignas(128) bf16_t As[128 * 64];
    __shared__ alignas(128) bf16_t Bs[128 * 64];
    const int tid = threadIdx.x, w = tid >> 6, l = tid & 63;
    const int rowA0 = blockIdx.y * 128, colB0 = blockIdx.x * 128;
    f32x4 acc[4][4] = {};
    gemm_core(A, Bt, 1024, rowA0, colB0, w, l, As, Bs, acc);
    const int wr = w >> 1, wc = w & 1;
#pragma unroll
    for (int m = 0; m < 4; ++m)
#pragma unroll
        for (int n = 0; n < 4; ++n) {
            int c = colB0 + wc * 64 + n * 16 + (l & 15);
            int rbase = rowA0 + wr * 64 + m * 16 + (l >> 4) * 4;
#pragma unroll
            for (int r = 0; r < 4; ++r)
                out[(size_t)(rbase + r) * 1024 + c] = acc[m][n][r];
        }
}

// ---------------- flash attention v3: swapped QK^T, in-register softmax ----------------
// Block: 128 q-rows of one (b,h); 4 waves x 32 rows (two 16-row sub-blocks m=0,1).
// S^T = mfma(K, Q): lane owns a q-row (q = lane&15) -> softmax fully in-register.
// P granule matches mfma_16x16x16 A-frag -> PV direct from registers (no P LDS).
__global__ __launch_bounds__(256, 4) void k_attn(const bf16_t* __restrict__ qb,
                                                 const bf16_t* __restrict__ kb,
                                                 const bf16_t* __restrict__ vb,
                                                 bf16_t* __restrict__ ob) {
    __shared__ alignas(128) bf16_t Ks[2][64 * 64];
    __shared__ alignas(128) bf16_t Vs[2][64 * 64];
    const int tid = threadIdx.x, w = tid >> 6, l = tid & 63;
    const int g = l >> 4;
    const int bid = blockIdx.x;                       // 0..1023
    const int bs = (bid & 7) * 128 + (bid >> 3);      // XCD-aware bijective swizzle
    const int bh = bs >> 3, bi = bh >> 4, h = bh & 15;
    const int q0 = (bs & 7) * 128;
    const bf16_t* qbase = qb + (size_t)bh * 1024 * 64;
    const bf16_t* kbase = kb + (size_t)bh * 1024 * 64;
    const bf16_t* vbase = vb + (size_t)bh * 64 * 1024;

    // Q fragments (B-operand of swapped QK^T): wave's 32 rows as two 16-row blocks
    bf16x8 qf[2][2];
#pragma unroll
    for (int m = 0; m < 2; ++m) {
        int qrow = q0 + m * 64 + w * 16 + (l & 15);
#pragma unroll
        for (int kk = 0; kk < 2; ++kk)
            qf[m][kk] = *reinterpret_cast<const bf16x8*>(
                qbase + (size_t)qrow * 64 + kk * 32 + g * 8);
    }

    float m_run[2] = {-1e30f, -1e30f};
    float l_run[2] = {0.f, 0.f};
    f32x4 o_acc[2][4] = {};

    // staging: linear LDS dest, inverse-swizzled global source (rule #21)
    const int srow = l >> 3;
    const int sc = 8 * ((l & 7) ^ srow);
#define STAGE(buf, kv0)                                                                   \
    {                                                                                     \
        _Pragma("unroll")                                                                 \
        for (int i = 0; i < 2; ++i) {                                                     \
            int rr = (i * 4 + w) * 8 + srow;                                              \
            __builtin_amdgcn_global_load_lds(AS1C(kbase + (size_t)((kv0) + rr) * 64 + sc),\
                                             AS3(&Ks[buf][(i * 4 + w) * 512]), 16, 0, 0); \
            __builtin_amdgcn_global_load_lds(AS1C(vbase + (size_t)rr * 1024 + (kv0) + sc),\
                                             AS3(&Vs[buf][(i * 4 + w) * 512]), 16, 0, 0); \
        }                                                                                 \
    }

    STAGE(0, 0);
    __syncthreads();

    const float SCL = 1.4426950408889634f / 64.0f;   // scale in log2 domain
    int cur = 0;
    for (int t = 0; t < 16; ++t) {
        if (t < 15) STAGE(cur ^ 1, (t + 1) * 64);

        // ---- S^T = K @ Q^T : sacc[m][n][r] = S[kv = n*16+g*4+r][q = l&15] ----
        f32x4 sacc[2][4] = {};
#pragma unroll
        for (int kk = 0; kk < 2; ++kk)
#pragma unroll
            for (int n = 0; n < 4; ++n) {
                int rr = n * 16 + (l & 15);
                int ec = (kk * 32 + g * 8) ^ ((l & 7) << 3);
                bf16x8 kfr = *reinterpret_cast<const bf16x8*>(&Ks[cur][rr * 64 + ec]);
                sacc[0][n] = __builtin_amdgcn_mfma_f32_16x16x32_bf16(kfr, qf[0][kk], sacc[0][n], 0, 0, 0);
                sacc[1][n] = __builtin_amdgcn_mfma_f32_16x16x32_bf16(kfr, qf[1][kk], sacc[1][n], 0, 0, 0);
            }

        // ---- in-register online softmax (lane owns q-row l&15; 16 kv vals/lane) ----
        s16x4 pa[2][4];
#pragma unroll
        for (int m = 0; m < 2; ++m) {
            float mxr = -1e30f;
#pragma unroll
            for (int n = 0; n < 4; ++n)
#pragma unroll
                for (int r = 0; r < 4; ++r) mxr = fmaxf(mxr, sacc[m][n][r]);
            mxr = fmaxf(mxr, __shfl_xor(mxr, 16, 64));
            mxr = fmaxf(mxr, __shfl_xor(mxr, 32, 64));
            float mx = mxr * SCL;
            float mo = m_run[m];
            if (__any(mx > mo + 8.0f)) {                 // defer-max (T13)
                float mn = fmaxf(mo, mx);
                float corr = fast_exp2(mo - mn);
                l_run[m] *= corr;
                m_run[m] = mn; mo = mn;
#pragma unroll
                for (int r = 0; r < 4; ++r) {
                    float c2 = __shfl(corr, (l & 48) | (g * 4 + r), 64);
#pragma unroll
                    for (int n = 0; n < 4; ++n) o_acc[m][n][r] *= c2;
                }
            }
            float lsum = 0.f;
#pragma unroll
            for (int n = 0; n < 4; ++n) {
                bf16x4 pb;
#pragma unroll
                for (int r = 0; r < 4; ++r) {
                    float pv = fast_exp2(fmaf(sacc[m][n][r], SCL, -mo));
                    lsum += pv;
                    pb[r] = (bf16_t)pv;
                }
                pa[m][n] = __builtin_bit_cast(s16x4, pb);
            }
            l_run[m] += lsum;
        }

        // ---- O += P @ V : PV via 16x16x16, A-frag = pa direct from registers ----
        const char* vrow = (const char*)&Vs[cur][0] + (l & 15) * 128;
#pragma unroll
        for (int c = 0; c < 4; ++c) {
            int kvb = (c * 32 + g * 8) ^ ((l & 7) << 4);
#pragma unroll
            for (int nd = 0; nd < 4; ++nd) {
                s16x4 vf = *reinterpret_cast<const s16x4*>(vrow + nd * 2048 + kvb);
                o_acc[0][nd] = __builtin_amdgcn_mfma_f32_16x16x16bf16_1k(pa[0][c], vf, o_acc[0][nd], 0, 0, 0);
                o_acc[1][nd] = __builtin_amdgcn_mfma_f32_16x16x16bf16_1k(pa[1][c], vf, o_acc[1][nd], 0, 0, 0);
            }
        }
        __syncthreads();
        cur ^= 1;
    }

    // ---- epilogue: reduce l across g-groups, normalize, write ----
#pragma unroll
    for (int m = 0; m < 2; ++m) {
        float ls = l_run[m];
        ls += __shfl_xor(ls, 16, 64);
        ls += __shfl_xor(ls, 32, 64);
        float inv = 1.0f / ls;                 // valid at lanes with q = l&15
#pragma unroll
        for (int r = 0; r < 4; ++r) {
            float c2 = __shfl(inv, (l & 48) | (g * 4 + r), 64);
            int row = q0 + m * 64 + w * 16 + g * 4 + r;
#pragma unroll
            for (int n = 0; n < 4; ++n)
                ob[((size_t)bi * 1024 + row) * 1024 + h * 64 + n * 16 + (l & 15)] =
                    (bf16_t)(o_acc[m][n][r] * c2);
        }
    }
#undef STAGE
}

extern "C" void kernel_launch(void* const* d_in, const int* in_sizes, int n_in,
                              void* d_out, int out_size, void* d_ws, size_t ws_size,
                              hipStream_t stream) {
    (void)in_sizes; (void)n_in; (void)out_size; (void)ws_size;
    const float* x     = (const float*)d_in[0];
    const float* wqkv  = (const float*)d_in[1];
    const float* wproj = (const float*)d_in[2];
    char* ws = (char*)d_ws;

    bf16_t* xb  = (bf16_t*)(ws);
    bf16_t* wqT = (bf16_t*)(ws + 16777216ull);
    bf16_t* wpT = (bf16_t*)(ws + 23068672ull);
    bf16_t* qb  = (bf16_t*)(ws + 25165824ull);
    bf16_t* kb  = (bf16_t*)(ws + 41943040ull);
    bf16_t* vb  = (bf16_t*)(ws + 58720256ull);
    bf16_t* ob  = (bf16_t*)(ws + 75497472ull);
    float*  cosT = (float*)(ws + 92274688ull);
    float*  sinT = (float*)(ws + 92536832ull);

    k_cvt<<<8192, 256, 0, stream>>>(x, xb, 2097152);
    k_tconv<<<dim3(48, 16), 256, 0, stream>>>(wqkv, wqT, 1024, 3072);
    k_tconv<<<dim3(16, 16), 256, 0, stream>>>(wproj, wpT, 1024, 1024);
    k_tab<<<256, 256, 0, stream>>>(cosT, sinT);
    k_gemm_qkv<<<dim3(24, 64), 256, 0, stream>>>(xb, wqT, cosT, sinT, qb, kb, vb);
    k_attn<<<1024, 256, 0, stream>>>(qb, kb, vb, ob);
    k_gemm_out<<<dim3(8, 64), 256, 0, stream>>>(ob, wpT, (float*)d_out);
}

// Round 4
// 186.577 us; speedup vs baseline: 1.3731x; 1.0119x over previous
//
#include <hip/hip_runtime.h>
#include <hip/hip_bf16.h>
#include <math.h>

typedef __bf16 bf16_t;
typedef __attribute__((ext_vector_type(8))) __bf16 bf16x8;
typedef __attribute__((ext_vector_type(4))) __bf16 bf16x4;
typedef __attribute__((ext_vector_type(4))) short s16x4;
typedef __attribute__((ext_vector_type(4))) float f32x4;

#define AS1C(p) ((const __attribute__((address_space(1))) void*)(p))
#define AS3(p)  ((__attribute__((address_space(3))) void*)(p))

__device__ __forceinline__ float fast_exp2(float x) { return __builtin_amdgcn_exp2f(x); }

// ---------------- convert f32 -> bf16, 4 elems/thread ----------------
__global__ __launch_bounds__(256) void k_cvt(const float* __restrict__ in,
                                             bf16_t* __restrict__ out, int n4) {
    int i = blockIdx.x * 256 + threadIdx.x;
    if (i < n4) {
        float4 v = reinterpret_cast<const float4*>(in)[i];
        bf16x4 o;
        o[0] = (bf16_t)v.x; o[1] = (bf16_t)v.y; o[2] = (bf16_t)v.z; o[3] = (bf16_t)v.w;
        reinterpret_cast<bf16x4*>(out)[i] = o;
    }
}

// ------------- transpose + convert: in (R x C f32) -> out (C x R bf16) -------------
__global__ __launch_bounds__(256) void k_tconv(const float* __restrict__ in,
                                               bf16_t* __restrict__ out, int R, int C) {
    __shared__ float tile[64][65];
    int r0 = blockIdx.y * 64, c0 = blockIdx.x * 64;
#pragma unroll
    for (int i = 0; i < 16; ++i) {
        int e = i * 256 + threadIdx.x;
        int r = e >> 6, c = e & 63;
        tile[r][c] = in[(size_t)(r0 + r) * C + c0 + c];
    }
    __syncthreads();
#pragma unroll
    for (int i = 0; i < 16; ++i) {
        int e = i * 256 + threadIdx.x;
        int c = e >> 6, r = e & 63;
        out[(size_t)(c0 + c) * R + r0 + r] = (bf16_t)tile[r][c];
    }
}

// ---------------- RoPE cos/sin tables: [1024][64] f32 each ----------------
__global__ __launch_bounds__(256) void k_tab(float* __restrict__ cosT,
                                             float* __restrict__ sinT) {
    int i = blockIdx.x * 256 + threadIdx.x;  // 65536 total
    int l = i >> 6, d = i & 63;
    int hh = l >> 5, ww = l & 31;            // H = W = 32
    float pos = (d < 32) ? (-1.0f + (2.0f / 31.0f) * (float)hh)
                         : (-1.0f + (2.0f / 31.0f) * (float)ww);
    int fi = (d & 31) >> 1;                  // linspace(1,128,16)[fi]
    float fb = (1.0f + (127.0f / 15.0f) * (float)fi) * 3.14159265358979323846f;
    float fr = pos * fb;
    cosT[i] = cosf(fr);
    sinT[i] = sinf(fr);
}

// ---------------- 128x128xK bf16 MFMA GEMM core (gemm_bt, used by gemm_out) ----------------
__device__ __forceinline__ void gemm_core(const bf16_t* __restrict__ A,
                                          const bf16_t* __restrict__ Bt,
                                          int K, int rowA0, int colB0,
                                          int w, int l, bf16_t* As, bf16_t* Bs,
                                          f32x4 acc[4][4]) {
    const int wr = w >> 1, wc = w & 1;
    for (int kt = 0; kt < K; kt += 64) {
#pragma unroll
        for (int i = 0; i < 4; ++i) {
            int rr = (i * 4 + w) * 8 + (l >> 3);
            int ch = (l & 7) * 8;
            __builtin_amdgcn_global_load_lds(AS1C(A + (size_t)(rowA0 + rr) * K + kt + ch),
                                             AS3(As + (i * 4 + w) * 512), 16, 0, 0);
            __builtin_amdgcn_global_load_lds(AS1C(Bt + (size_t)(colB0 + rr) * K + kt + ch),
                                             AS3(Bs + (i * 4 + w) * 512), 16, 0, 0);
        }
        __syncthreads();
#pragma unroll
        for (int kk = 0; kk < 2; ++kk) {
            bf16x8 af[4], bfr[4];
#pragma unroll
            for (int m = 0; m < 4; ++m)
                af[m] = *reinterpret_cast<const bf16x8*>(
                    As + (wr * 64 + m * 16 + (l & 15)) * 64 + kk * 32 + (l >> 4) * 8);
#pragma unroll
            for (int n = 0; n < 4; ++n)
                bfr[n] = *reinterpret_cast<const bf16x8*>(
                    Bs + (wc * 64 + n * 16 + (l & 15)) * 64 + kk * 32 + (l >> 4) * 8);
#pragma unroll
            for (int m = 0; m < 4; ++m)
#pragma unroll
                for (int n = 0; n < 4; ++n)
                    acc[m][n] = __builtin_amdgcn_mfma_f32_16x16x32_bf16(af[m], bfr[n],
                                                                        acc[m][n], 0, 0, 0);
        }
        __syncthreads();
    }
}

// ---------------- GEMM1: qkv = xb @ w_qkv, 256x256 8-phase template + RoPE epilogue ----------
// 512 threads = 8 waves (2M x 4N); per-wave 128x64 output (acc[8][4]).
// Double-buffered 128 KiB LDS; counted vmcnt(8); T2 swizzle; setprio MFMA clusters.
__global__ __launch_bounds__(512, 2) void k_gemm_qkv(const bf16_t* __restrict__ A,
                                                     const bf16_t* __restrict__ Bt,
                                                     const float* __restrict__ cosT,
                                                     const float* __restrict__ sinT,
                                                     bf16_t* __restrict__ qb,
                                                     bf16_t* __restrict__ kb,
                                                     bf16_t* __restrict__ vb) {
    __shared__ alignas(128) bf16_t As[2][256 * 64];
    __shared__ alignas(128) bf16_t Bs[2][256 * 64];
    const int tid = threadIdx.x, w = tid >> 6, l = tid & 63;
    const int wr = w >> 2, wc = w & 3;
    const int bid = blockIdx.x;                 // 0..383 (= 32 M-blocks x 12 N-blocks)
    const int sw = (bid & 7) * 48 + (bid >> 3); // XCD-aware bijective swizzle (384 % 8 == 0)
    const int bx = sw % 12, by = sw / 12;
    const int rowA0 = by * 256, colB0 = bx * 256;
    const int sc = ((l & 7) ^ (l >> 3)) << 3;   // inverse-swizzled global col (rule #21)

    f32x4 acc[8][4] = {};

    // stage one K-tile (A: 4 glds, B: 4 glds; 8 KB per gld across 8 waves)
#define STG(dA, dB, kt)                                                                     \
    {                                                                                       \
        _Pragma("unroll")                                                                   \
        for (int j = 0; j < 4; ++j) {                                                       \
            int rr = j * 64 + w * 8 + (l >> 3);                                             \
            __builtin_amdgcn_global_load_lds(                                               \
                AS1C(A + (size_t)(rowA0 + rr) * 1024 + (kt) * 64 + sc),                     \
                AS3((dA) + (j * 64 + w * 8) * 64), 16, 0, 0);                               \
            __builtin_amdgcn_global_load_lds(                                               \
                AS1C(Bt + (size_t)(colB0 + rr) * 1024 + (kt) * 64 + sc),                    \
                AS3((dB) + (j * 64 + w * 8) * 64), 16, 0, 0);                               \
        }                                                                                   \
    }

    STG(&As[0][0], &Bs[0][0], 0);

    for (int T = 0; T < 16; ++T) {
        bf16_t* cA = &As[T & 1][0];
        bf16_t* cB = &Bs[T & 1][0];
        if (T < 15) {
            STG(&As[(T & 1) ^ 1][0], &Bs[(T & 1) ^ 1][0], T + 1);
            asm volatile("s_waitcnt vmcnt(8)" ::: "memory");   // tile T landed; T+1 in flight
        } else {
            asm volatile("s_waitcnt vmcnt(0)" ::: "memory");   // final drain (epilogue boundary)
        }
        __builtin_amdgcn_s_barrier();

#pragma unroll
        for (int kk = 0; kk < 2; ++kk) {
            const int ec = (kk * 32 + (l >> 4) * 8) ^ ((l & 7) << 3);
            bf16x8 af[4], bfr[4];
            // ---- phase (kk, m-half 0): 8 ds_reads + 16 MFMA ----
#pragma unroll
            for (int n = 0; n < 4; ++n)
                bfr[n] = *reinterpret_cast<const bf16x8*>(
                    cB + (wc * 64 + n * 16 + (l & 15)) * 64 + ec);
#pragma unroll
            for (int mm = 0; mm < 4; ++mm)
                af[mm] = *reinterpret_cast<const bf16x8*>(
                    cA + (wr * 128 + mm * 16 + (l & 15)) * 64 + ec);
            asm volatile("s_waitcnt lgkmcnt(0)" ::: "memory");
            __builtin_amdgcn_sched_barrier(0);
            __builtin_amdgcn_s_setprio(1);
#pragma unroll
            for (int mm = 0; mm < 4; ++mm)
#pragma unroll
                for (int n = 0; n < 4; ++n)
                    acc[mm][n] = __builtin_amdgcn_mfma_f32_16x16x32_bf16(af[mm], bfr[n],
                                                                         acc[mm][n], 0, 0, 0);
            __builtin_amdgcn_s_setprio(0);
            __builtin_amdgcn_s_barrier();
            // ---- phase (kk, m-half 1): 4 ds_reads + 16 MFMA (reuse bfr) ----
#pragma unroll
            for (int mm = 0; mm < 4; ++mm)
                af[mm] = *reinterpret_cast<const bf16x8*>(
                    cA + (wr * 128 + (4 + mm) * 16 + (l & 15)) * 64 + ec);
            asm volatile("s_waitcnt lgkmcnt(0)" ::: "memory");
            __builtin_amdgcn_sched_barrier(0);
            __builtin_amdgcn_s_setprio(1);
#pragma unroll
            for (int mm = 0; mm < 4; ++mm)
#pragma unroll
                for (int n = 0; n < 4; ++n)
                    acc[4 + mm][n] = __builtin_amdgcn_mfma_f32_16x16x32_bf16(af[mm], bfr[n],
                                                                             acc[4 + mm][n], 0, 0, 0);
            __builtin_amdgcn_s_setprio(0);
            __builtin_amdgcn_s_barrier();
        }
    }
#undef STG

    // ---- epilogue: RoPE on q/k, transposed scatter for v ----
    const int part = colB0 >> 10;   // bx 0-3 -> q, 4-7 -> k, 8-11 -> v
#pragma unroll
    for (int m = 0; m < 8; ++m) {
#pragma unroll
        for (int n = 0; n < 4; ++n) {
            const int c = colB0 + wc * 64 + n * 16 + (l & 15);
            const int head = (c & 1023) >> 6;
            const int d = c & 63;
            const int rbase = rowA0 + wr * 128 + m * 16 + (l >> 4) * 4;
            if (part == 2) {
#pragma unroll
                for (int r = 0; r < 4; ++r) {
                    int row = rbase + r;
                    int bb = row >> 10, ll = row & 1023;
                    vb[(((size_t)bb * 16 + head) * 64 + d) * 1024 + ll] = (bf16_t)acc[m][n][r];
                }
            } else {
                bf16_t* dst = (part == 0) ? qb : kb;
#pragma unroll
                for (int r = 0; r < 4; ++r) {
                    int row = rbase + r;
                    int bb = row >> 10, ll = row & 1023;
                    float v0 = acc[m][n][r];
                    float vp = __shfl_xor(v0, 1, 64);
                    float cs = cosT[ll * 64 + d];
                    float sn = sinT[ll * 64 + d];
                    float res = (d & 1) ? fmaf(vp, sn, v0 * cs) : fmaf(-vp, sn, v0 * cs);
                    dst[(((size_t)bb * 16 + head) * 1024 + ll) * 64 + d] = (bf16_t)res;
                }
            }
        }
    }
}

// ---------------- GEMM2: out = ob @ w_proj, f32 epilogue ----------------
__global__ __launch_bounds__(256) void k_gemm_out(const bf16_t* __restrict__ A,
                                                  const bf16_t* __restrict__ Bt,
                                                  float* __restrict__ out) {
    __shared__ alignas(128) bf16_t As[128 * 64];
    __shared__ alignas(128) bf16_t Bs[128 * 64];
    const int tid = threadIdx.x, w = tid >> 6, l = tid & 63;
    const int rowA0 = blockIdx.y * 128, colB0 = blockIdx.x * 128;
    f32x4 acc[4][4] = {};
    gemm_core(A, Bt, 1024, rowA0, colB0, w, l, As, Bs, acc);
    const int wr = w >> 1, wc = w & 1;
#pragma unroll
    for (int m = 0; m < 4; ++m)
#pragma unroll
        for (int n = 0; n < 4; ++n) {
            int c = colB0 + wc * 64 + n * 16 + (l & 15);
            int rbase = rowA0 + wr * 64 + m * 16 + (l >> 4) * 4;
#pragma unroll
            for (int r = 0; r < 4; ++r)
                out[(size_t)(rbase + r) * 1024 + c] = acc[m][n][r];
        }
}

// ---------------- flash attention v3: swapped QK^T, in-register softmax ----------------
__global__ __launch_bounds__(256, 4) void k_attn(const bf16_t* __restrict__ qb,
                                                 const bf16_t* __restrict__ kb,
                                                 const bf16_t* __restrict__ vb,
                                                 bf16_t* __restrict__ ob) {
    __shared__ alignas(128) bf16_t Ks[2][64 * 64];
    __shared__ alignas(128) bf16_t Vs[2][64 * 64];
    const int tid = threadIdx.x, w = tid >> 6, l = tid & 63;
    const int g = l >> 4;
    const int bid = blockIdx.x;                       // 0..1023
    const int bs = (bid & 7) * 128 + (bid >> 3);      // XCD-aware bijective swizzle
    const int bh = bs >> 3, bi = bh >> 4, h = bh & 15;
    const int q0 = (bs & 7) * 128;
    const bf16_t* qbase = qb + (size_t)bh * 1024 * 64;
    const bf16_t* kbase = kb + (size_t)bh * 1024 * 64;
    const bf16_t* vbase = vb + (size_t)bh * 64 * 1024;

    bf16x8 qf[2][2];
#pragma unroll
    for (int m = 0; m < 2; ++m) {
        int qrow = q0 + m * 64 + w * 16 + (l & 15);
#pragma unroll
        for (int kk = 0; kk < 2; ++kk)
            qf[m][kk] = *reinterpret_cast<const bf16x8*>(
                qbase + (size_t)qrow * 64 + kk * 32 + g * 8);
    }

    float m_run[2] = {-1e30f, -1e30f};
    float l_run[2] = {0.f, 0.f};
    f32x4 o_acc[2][4] = {};

    const int srow = l >> 3;
    const int sc = 8 * ((l & 7) ^ srow);
#define STAGE(buf, kv0)                                                                   \
    {                                                                                     \
        _Pragma("unroll")                                                                 \
        for (int i = 0; i < 2; ++i) {                                                     \
            int rr = (i * 4 + w) * 8 + srow;                                              \
            __builtin_amdgcn_global_load_lds(AS1C(kbase + (size_t)((kv0) + rr) * 64 + sc),\
                                             AS3(&Ks[buf][(i * 4 + w) * 512]), 16, 0, 0); \
            __builtin_amdgcn_global_load_lds(AS1C(vbase + (size_t)rr * 1024 + (kv0) + sc),\
                                             AS3(&Vs[buf][(i * 4 + w) * 512]), 16, 0, 0); \
        }                                                                                 \
    }

    STAGE(0, 0);
    __syncthreads();

    const float SCL = 1.4426950408889634f / 64.0f;
    int cur = 0;
    for (int t = 0; t < 16; ++t) {
        if (t < 15) STAGE(cur ^ 1, (t + 1) * 64);

        f32x4 sacc[2][4] = {};
#pragma unroll
        for (int kk = 0; kk < 2; ++kk)
#pragma unroll
            for (int n = 0; n < 4; ++n) {
                int rr = n * 16 + (l & 15);
                int ec = (kk * 32 + g * 8) ^ ((l & 7) << 3);
                bf16x8 kfr = *reinterpret_cast<const bf16x8*>(&Ks[cur][rr * 64 + ec]);
                sacc[0][n] = __builtin_amdgcn_mfma_f32_16x16x32_bf16(kfr, qf[0][kk], sacc[0][n], 0, 0, 0);
                sacc[1][n] = __builtin_amdgcn_mfma_f32_16x16x32_bf16(kfr, qf[1][kk], sacc[1][n], 0, 0, 0);
            }

        s16x4 pa[2][4];
#pragma unroll
        for (int m = 0; m < 2; ++m) {
            float mxr = -1e30f;
#pragma unroll
            for (int n = 0; n < 4; ++n)
#pragma unroll
                for (int r = 0; r < 4; ++r) mxr = fmaxf(mxr, sacc[m][n][r]);
            mxr = fmaxf(mxr, __shfl_xor(mxr, 16, 64));
            mxr = fmaxf(mxr, __shfl_xor(mxr, 32, 64));
            float mx = mxr * SCL;
            float mo = m_run[m];
            if (__any(mx > mo + 8.0f)) {
                float mn = fmaxf(mo, mx);
                float corr = fast_exp2(mo - mn);
                l_run[m] *= corr;
                m_run[m] = mn; mo = mn;
#pragma unroll
                for (int r = 0; r < 4; ++r) {
                    float c2 = __shfl(corr, (l & 48) | (g * 4 + r), 64);
#pragma unroll
                    for (int n = 0; n < 4; ++n) o_acc[m][n][r] *= c2;
                }
            }
            float lsum = 0.f;
#pragma unroll
            for (int n = 0; n < 4; ++n) {
                bf16x4 pb;
#pragma unroll
                for (int r = 0; r < 4; ++r) {
                    float pv = fast_exp2(fmaf(sacc[m][n][r], SCL, -mo));
                    lsum += pv;
                    pb[r] = (bf16_t)pv;
                }
                pa[m][n] = __builtin_bit_cast(s16x4, pb);
            }
            l_run[m] += lsum;
        }

        const char* vrow = (const char*)&Vs[cur][0] + (l & 15) * 128;
#pragma unroll
        for (int c = 0; c < 4; ++c) {
            int kvb = (c * 32 + g * 8) ^ ((l & 7) << 4);
#pragma unroll
            for (int nd = 0; nd < 4; ++nd) {
                s16x4 vf = *reinterpret_cast<const s16x4*>(vrow + nd * 2048 + kvb);
                o_acc[0][nd] = __builtin_amdgcn_mfma_f32_16x16x16bf16_1k(pa[0][c], vf, o_acc[0][nd], 0, 0, 0);
                o_acc[1][nd] = __builtin_amdgcn_mfma_f32_16x16x16bf16_1k(pa[1][c], vf, o_acc[1][nd], 0, 0, 0);
            }
        }
        __syncthreads();
        cur ^= 1;
    }

#pragma unroll
    for (int m = 0; m < 2; ++m) {
        float ls = l_run[m];
        ls += __shfl_xor(ls, 16, 64);
        ls += __shfl_xor(ls, 32, 64);
        float inv = 1.0f / ls;
#pragma unroll
        for (int r = 0; r < 4; ++r) {
            float c2 = __shfl(inv, (l & 48) | (g * 4 + r), 64);
            int row = q0 + m * 64 + w * 16 + g * 4 + r;
#pragma unroll
            for (int n = 0; n < 4; ++n)
                ob[((size_t)bi * 1024 + row) * 1024 + h * 64 + n * 16 + (l & 15)] =
                    (bf16_t)(o_acc[m][n][r] * c2);
        }
    }
#undef STAGE
}

extern "C" void kernel_launch(void* const* d_in, const int* in_sizes, int n_in,
                              void* d_out, int out_size, void* d_ws, size_t ws_size,
                              hipStream_t stream) {
    (void)in_sizes; (void)n_in; (void)out_size; (void)ws_size;
    const float* x     = (const float*)d_in[0];
    const float* wqkv  = (const float*)d_in[1];
    const float* wproj = (const float*)d_in[2];
    char* ws = (char*)d_ws;

    bf16_t* xb  = (bf16_t*)(ws);
    bf16_t* wqT = (bf16_t*)(ws + 16777216ull);
    bf16_t* wpT = (bf16_t*)(ws + 23068672ull);
    bf16_t* qb  = (bf16_t*)(ws + 25165824ull);
    bf16_t* kb  = (bf16_t*)(ws + 41943040ull);
    bf16_t* vb  = (bf16_t*)(ws + 58720256ull);
    bf16_t* ob  = (bf16_t*)(ws + 75497472ull);
    float*  cosT = (float*)(ws + 92274688ull);
    float*  sinT = (float*)(ws + 92536832ull);

    k_cvt<<<8192, 256, 0, stream>>>(x, xb, 2097152);
    k_tconv<<<dim3(48, 16), 256, 0, stream>>>(wqkv, wqT, 1024, 3072);
    k_tconv<<<dim3(16, 16), 256, 0, stream>>>(wproj, wpT, 1024, 1024);
    k_tab<<<256, 256, 0, stream>>>(cosT, sinT);
    k_gemm_qkv<<<384, 512, 0, stream>>>(xb, wqT, cosT, sinT, qb, kb, vb);
    k_attn<<<1024, 256, 0, stream>>>(qb, kb, vb, ob);
    k_gemm_out<<<dim3(8, 64), 256, 0, stream>>>(ob, wpT, (float*)d_out);
}

// Round 5
// 162.950 us; speedup vs baseline: 1.5722x; 1.1450x over previous
//
#include <hip/hip_runtime.h>
#include <hip/hip_bf16.h>
#include <math.h>

typedef __bf16 bf16_t;
typedef __attribute__((ext_vector_type(8))) __bf16 bf16x8;
typedef __attribute__((ext_vector_type(4))) __bf16 bf16x4;
typedef __attribute__((ext_vector_type(4))) short s16x4;
typedef __attribute__((ext_vector_type(4))) float f32x4;

#define AS1C(p) ((const __attribute__((address_space(1))) void*)(p))
#define AS3(p)  ((__attribute__((address_space(3))) void*)(p))

__device__ __forceinline__ float fast_exp2(float x) { return __builtin_amdgcn_exp2f(x); }

// ---------------- convert f32 -> bf16, 4 elems/thread ----------------
__global__ __launch_bounds__(256) void k_cvt(const float* __restrict__ in,
                                             bf16_t* __restrict__ out, int n4) {
    int i = blockIdx.x * 256 + threadIdx.x;
    if (i < n4) {
        float4 v = reinterpret_cast<const float4*>(in)[i];
        bf16x4 o;
        o[0] = (bf16_t)v.x; o[1] = (bf16_t)v.y; o[2] = (bf16_t)v.z; o[3] = (bf16_t)v.w;
        reinterpret_cast<bf16x4*>(out)[i] = o;
    }
}

// ------------- transpose + convert: in (R x C f32) -> out (C x R bf16) -------------
__global__ __launch_bounds__(256) void k_tconv(const float* __restrict__ in,
                                               bf16_t* __restrict__ out, int R, int C) {
    __shared__ float tile[64][65];
    int r0 = blockIdx.y * 64, c0 = blockIdx.x * 64;
#pragma unroll
    for (int i = 0; i < 16; ++i) {
        int e = i * 256 + threadIdx.x;
        int r = e >> 6, c = e & 63;
        tile[r][c] = in[(size_t)(r0 + r) * C + c0 + c];
    }
    __syncthreads();
#pragma unroll
    for (int i = 0; i < 16; ++i) {
        int e = i * 256 + threadIdx.x;
        int c = e >> 6, r = e & 63;
        out[(size_t)(c0 + c) * R + r0 + r] = (bf16_t)tile[r][c];
    }
}

// ---------------- RoPE cos/sin tables: [1024][64] f32 each ----------------
__global__ __launch_bounds__(256) void k_tab(float* __restrict__ cosT,
                                             float* __restrict__ sinT) {
    int i = blockIdx.x * 256 + threadIdx.x;  // 65536 total
    int l = i >> 6, d = i & 63;
    int hh = l >> 5, ww = l & 31;            // H = W = 32
    float pos = (d < 32) ? (-1.0f + (2.0f / 31.0f) * (float)hh)
                         : (-1.0f + (2.0f / 31.0f) * (float)ww);
    int fi = (d & 31) >> 1;                  // linspace(1,128,16)[fi]
    float fb = (1.0f + (127.0f / 15.0f) * (float)fi) * 3.14159265358979323846f;
    float fr = pos * fb;
    cosT[i] = cosf(fr);
    sinT[i] = sinf(fr);
}

// ---------------- 128x128 double-buffered pipelined GEMM core (K=1024) ----------------
// 4 waves (2M x 2N), per-wave 64x64 (acc[4][4]). 64 KiB LDS -> 2 blocks/CU.
// Counted vmcnt(8) depth-1 prefetch, 2 barriers/tile, T2 swizzle (conflict-free reads).
__device__ __forceinline__ void gemm128_pipe(const bf16_t* __restrict__ A,
                                             const bf16_t* __restrict__ Bt,
                                             int rowA0, int colB0, int w, int l,
                                             bf16_t* As, bf16_t* Bs,  // each [2][128*64]
                                             f32x4 acc[4][4]) {
    const int wr = w >> 1, wc = w & 1;
    const int r8 = l >> 3;
    const int sc = ((l & 7) ^ r8) << 3;   // inverse-swizzled global col (rule #21)

#define STG8(buf, kt)                                                                      \
    {                                                                                      \
        _Pragma("unroll")                                                                  \
        for (int j = 0; j < 4; ++j) {                                                      \
            int rr = j * 32 + w * 8 + r8;                                                  \
            __builtin_amdgcn_global_load_lds(                                              \
                AS1C(A + (size_t)(rowA0 + rr) * 1024 + (kt) * 64 + sc),                    \
                AS3(As + (buf) * 8192 + (j * 32 + w * 8) * 64), 16, 0, 0);                 \
            __builtin_amdgcn_global_load_lds(                                              \
                AS1C(Bt + (size_t)(colB0 + rr) * 1024 + (kt) * 64 + sc),                   \
                AS3(Bs + (buf) * 8192 + (j * 32 + w * 8) * 64), 16, 0, 0);                 \
        }                                                                                  \
    }

    STG8(0, 0);
    for (int T = 0; T < 16; ++T) {
        if (T < 15) {
            STG8((T + 1) & 1, T + 1);
            asm volatile("s_waitcnt vmcnt(8)" ::: "memory");   // tile T landed; T+1 in flight
        } else {
            asm volatile("s_waitcnt vmcnt(0)" ::: "memory");
        }
        __builtin_amdgcn_s_barrier();
        const bf16_t* cA = As + (T & 1) * 8192;
        const bf16_t* cB = Bs + (T & 1) * 8192;
#pragma unroll
        for (int kk = 0; kk < 2; ++kk) {
            const int ec = (kk * 32 + (l >> 4) * 8) ^ ((l & 7) << 3);
            bf16x8 af[4], bfr[4];
#pragma unroll
            for (int mm = 0; mm < 4; ++mm)
                af[mm] = *reinterpret_cast<const bf16x8*>(
                    cA + (wr * 64 + mm * 16 + (l & 15)) * 64 + ec);
#pragma unroll
            for (int n = 0; n < 4; ++n)
                bfr[n] = *reinterpret_cast<const bf16x8*>(
                    cB + (wc * 64 + n * 16 + (l & 15)) * 64 + ec);
            asm volatile("s_waitcnt lgkmcnt(0)" ::: "memory");
            __builtin_amdgcn_sched_barrier(0);
            __builtin_amdgcn_s_setprio(1);
#pragma unroll
            for (int mm = 0; mm < 4; ++mm)
#pragma unroll
                for (int n = 0; n < 4; ++n)
                    acc[mm][n] = __builtin_amdgcn_mfma_f32_16x16x32_bf16(af[mm], bfr[n],
                                                                         acc[mm][n], 0, 0, 0);
            __builtin_amdgcn_s_setprio(0);
        }
        __builtin_amdgcn_s_barrier();   // all reads of buf[T&1] done -> safe to restage
    }
#undef STG8
}

// ---------------- GEMM1: qkv = xb @ w_qkv, 128^2 pipelined core + RoPE epilogue ----------
__global__ __launch_bounds__(256, 2) void k_gemm_qkv(const bf16_t* __restrict__ A,
                                                     const bf16_t* __restrict__ Bt,
                                                     const float* __restrict__ cosT,
                                                     const float* __restrict__ sinT,
                                                     bf16_t* __restrict__ qb,
                                                     bf16_t* __restrict__ kb,
                                                     bf16_t* __restrict__ vb) {
    __shared__ alignas(128) char smem[65536];
    bf16_t* As = (bf16_t*)smem;
    bf16_t* Bs = (bf16_t*)(smem + 32768);
    const int tid = threadIdx.x, w = tid >> 6, l = tid & 63;
    const int wr = w >> 1, wc = w & 1;
    const int bid = blockIdx.x;                   // 0..1535 (64 M-blocks x 24 N-blocks)
    const int sw = (bid & 7) * 192 + (bid >> 3);  // XCD-aware bijective swizzle
    const int bx = sw % 24, by = sw / 24;
    const int rowA0 = by * 128, colB0 = bx * 128;

    f32x4 acc[4][4] = {};
    gemm128_pipe(A, Bt, rowA0, colB0, w, l, As, Bs, acc);

    const int part = colB0 >> 10;   // bx 0-7 -> q, 8-15 -> k, 16-23 -> v
    if (part == 2) {
        // ---- v: transpose via LDS, coalesced (dh, L) stores ----
        __builtin_amdgcn_sched_barrier(0);
        __syncthreads();
        bf16_t* Tb = (bf16_t*)smem;  // [128][136]
#pragma unroll
        for (int m = 0; m < 4; ++m)
#pragma unroll
            for (int n = 0; n < 4; ++n) {
                int cc = wc * 64 + n * 16 + (l & 15);
                int rr = wr * 64 + m * 16 + (l >> 4) * 4;
#pragma unroll
                for (int r = 0; r < 4; ++r)
                    Tb[cc * 136 + rr + r] = (bf16_t)acc[m][n][r];
            }
        __syncthreads();
        const int j = tid >> 1, half = tid & 1;
        const int c = colB0 + j;
        const int head = (c & 1023) >> 6, d = c & 63;
        const int bb = rowA0 >> 10, ll0 = rowA0 & 1023;
        bf16_t* dst = vb + (((size_t)bb * 16 + head) * 64 + d) * 1024 + ll0 + half * 64;
        const bf16_t* srcp = Tb + j * 136 + half * 64;
#pragma unroll
        for (int e = 0; e < 8; ++e)
            *reinterpret_cast<bf16x8*>(dst + e * 8) =
                *reinterpret_cast<const bf16x8*>(srcp + e * 8);
    } else {
        bf16_t* dstb = (part == 0) ? qb : kb;
#pragma unroll
        for (int m = 0; m < 4; ++m)
#pragma unroll
            for (int n = 0; n < 4; ++n) {
                const int c = colB0 + wc * 64 + n * 16 + (l & 15);
                const int head = (c & 1023) >> 6;
                const int d = c & 63;
                const int rbase = rowA0 + wr * 64 + m * 16 + (l >> 4) * 4;
#pragma unroll
                for (int r = 0; r < 4; ++r) {
                    int row = rbase + r;
                    int bb = row >> 10, ll = row & 1023;
                    float v0 = acc[m][n][r];
                    float vp = __shfl_xor(v0, 1, 64);
                    float cs = cosT[ll * 64 + d];
                    float sn = sinT[ll * 64 + d];
                    float res = (d & 1) ? fmaf(vp, sn, v0 * cs) : fmaf(-vp, sn, v0 * cs);
                    dstb[(((size_t)bb * 16 + head) * 1024 + ll) * 64 + d] = (bf16_t)res;
                }
            }
    }
}

// ---------------- GEMM2: out = ob @ w_proj, 128^2 pipelined core, f32 epilogue ----------
__global__ __launch_bounds__(256, 2) void k_gemm_out(const bf16_t* __restrict__ A,
                                                     const bf16_t* __restrict__ Bt,
                                                     float* __restrict__ out) {
    __shared__ alignas(128) char smem[65536];
    bf16_t* As = (bf16_t*)smem;
    bf16_t* Bs = (bf16_t*)(smem + 32768);
    const int tid = threadIdx.x, w = tid >> 6, l = tid & 63;
    const int wr = w >> 1, wc = w & 1;
    const int bid = blockIdx.x;                  // 0..511 (64 M-blocks x 8 N-blocks)
    const int sw = (bid & 7) * 64 + (bid >> 3);  // XCD-aware bijective swizzle
    const int bx = sw & 7, by = sw >> 3;
    const int rowA0 = by * 128, colB0 = bx * 128;

    f32x4 acc[4][4] = {};
    gemm128_pipe(A, Bt, rowA0, colB0, w, l, As, Bs, acc);

#pragma unroll
    for (int m = 0; m < 4; ++m)
#pragma unroll
        for (int n = 0; n < 4; ++n) {
            int c = colB0 + wc * 64 + n * 16 + (l & 15);
            int rbase = rowA0 + wr * 64 + m * 16 + (l >> 4) * 4;
#pragma unroll
            for (int r = 0; r < 4; ++r)
                out[(size_t)(rbase + r) * 1024 + c] = acc[m][n][r];
        }
}

// ---------------- flash attention v3: swapped QK^T, in-register softmax ----------------
__global__ __launch_bounds__(256, 4) void k_attn(const bf16_t* __restrict__ qb,
                                                 const bf16_t* __restrict__ kb,
                                                 const bf16_t* __restrict__ vb,
                                                 bf16_t* __restrict__ ob) {
    __shared__ alignas(128) bf16_t Ks[2][64 * 64];
    __shared__ alignas(128) bf16_t Vs[2][64 * 64];
    const int tid = threadIdx.x, w = tid >> 6, l = tid & 63;
    const int g = l >> 4;
    const int bid = blockIdx.x;                       // 0..1023
    const int bs = (bid & 7) * 128 + (bid >> 3);      // XCD-aware bijective swizzle
    const int bh = bs >> 3, bi = bh >> 4, h = bh & 15;
    const int q0 = (bs & 7) * 128;
    const bf16_t* qbase = qb + (size_t)bh * 1024 * 64;
    const bf16_t* kbase = kb + (size_t)bh * 1024 * 64;
    const bf16_t* vbase = vb + (size_t)bh * 64 * 1024;

    bf16x8 qf[2][2];
#pragma unroll
    for (int m = 0; m < 2; ++m) {
        int qrow = q0 + m * 64 + w * 16 + (l & 15);
#pragma unroll
        for (int kk = 0; kk < 2; ++kk)
            qf[m][kk] = *reinterpret_cast<const bf16x8*>(
                qbase + (size_t)qrow * 64 + kk * 32 + g * 8);
    }

    float m_run[2] = {-1e30f, -1e30f};
    float l_run[2] = {0.f, 0.f};
    f32x4 o_acc[2][4] = {};

    const int srow = l >> 3;
    const int sc = 8 * ((l & 7) ^ srow);
#define STAGE(buf, kv0)                                                                   \
    {                                                                                     \
        _Pragma("unroll")                                                                 \
        for (int i = 0; i < 2; ++i) {                                                     \
            int rr = (i * 4 + w) * 8 + srow;                                              \
            __builtin_amdgcn_global_load_lds(AS1C(kbase + (size_t)((kv0) + rr) * 64 + sc),\
                                             AS3(&Ks[buf][(i * 4 + w) * 512]), 16, 0, 0); \
            __builtin_amdgcn_global_load_lds(AS1C(vbase + (size_t)rr * 1024 + (kv0) + sc),\
                                             AS3(&Vs[buf][(i * 4 + w) * 512]), 16, 0, 0); \
        }                                                                                 \
    }

    STAGE(0, 0);
    __syncthreads();

    const float SCL = 1.4426950408889634f / 64.0f;
    int cur = 0;
    for (int t = 0; t < 16; ++t) {
        if (t < 15) STAGE(cur ^ 1, (t + 1) * 64);

        f32x4 sacc[2][4] = {};
#pragma unroll
        for (int kk = 0; kk < 2; ++kk)
#pragma unroll
            for (int n = 0; n < 4; ++n) {
                int rr = n * 16 + (l & 15);
                int ec = (kk * 32 + g * 8) ^ ((l & 7) << 3);
                bf16x8 kfr = *reinterpret_cast<const bf16x8*>(&Ks[cur][rr * 64 + ec]);
                sacc[0][n] = __builtin_amdgcn_mfma_f32_16x16x32_bf16(kfr, qf[0][kk], sacc[0][n], 0, 0, 0);
                sacc[1][n] = __builtin_amdgcn_mfma_f32_16x16x32_bf16(kfr, qf[1][kk], sacc[1][n], 0, 0, 0);
            }

        s16x4 pa[2][4];
#pragma unroll
        for (int m = 0; m < 2; ++m) {
            float mxr = -1e30f;
#pragma unroll
            for (int n = 0; n < 4; ++n)
#pragma unroll
                for (int r = 0; r < 4; ++r) mxr = fmaxf(mxr, sacc[m][n][r]);
            mxr = fmaxf(mxr, __shfl_xor(mxr, 16, 64));
            mxr = fmaxf(mxr, __shfl_xor(mxr, 32, 64));
            float mx = mxr * SCL;
            float mo = m_run[m];
            if (__any(mx > mo + 8.0f)) {
                float mn = fmaxf(mo, mx);
                float corr = fast_exp2(mo - mn);
                l_run[m] *= corr;
                m_run[m] = mn; mo = mn;
#pragma unroll
                for (int r = 0; r < 4; ++r) {
                    float c2 = __shfl(corr, (l & 48) | (g * 4 + r), 64);
#pragma unroll
                    for (int n = 0; n < 4; ++n) o_acc[m][n][r] *= c2;
                }
            }
            float lsum = 0.f;
#pragma unroll
            for (int n = 0; n < 4; ++n) {
                bf16x4 pb;
#pragma unroll
                for (int r = 0; r < 4; ++r) {
                    float pv = fast_exp2(fmaf(sacc[m][n][r], SCL, -mo));
                    lsum += pv;
                    pb[r] = (bf16_t)pv;
                }
                pa[m][n] = __builtin_bit_cast(s16x4, pb);
            }
            l_run[m] += lsum;
        }

        const char* vrow = (const char*)&Vs[cur][0] + (l & 15) * 128;
#pragma unroll
        for (int c = 0; c < 4; ++c) {
            int kvb = (c * 32 + g * 8) ^ ((l & 7) << 4);
#pragma unroll
            for (int nd = 0; nd < 4; ++nd) {
                s16x4 vf = *reinterpret_cast<const s16x4*>(vrow + nd * 2048 + kvb);
                o_acc[0][nd] = __builtin_amdgcn_mfma_f32_16x16x16bf16_1k(pa[0][c], vf, o_acc[0][nd], 0, 0, 0);
                o_acc[1][nd] = __builtin_amdgcn_mfma_f32_16x16x16bf16_1k(pa[1][c], vf, o_acc[1][nd], 0, 0, 0);
            }
        }
        __syncthreads();
        cur ^= 1;
    }

#pragma unroll
    for (int m = 0; m < 2; ++m) {
        float ls = l_run[m];
        ls += __shfl_xor(ls, 16, 64);
        ls += __shfl_xor(ls, 32, 64);
        float inv = 1.0f / ls;
#pragma unroll
        for (int r = 0; r < 4; ++r) {
            float c2 = __shfl(inv, (l & 48) | (g * 4 + r), 64);
            int row = q0 + m * 64 + w * 16 + g * 4 + r;
#pragma unroll
            for (int n = 0; n < 4; ++n)
                ob[((size_t)bi * 1024 + row) * 1024 + h * 64 + n * 16 + (l & 15)] =
                    (bf16_t)(o_acc[m][n][r] * c2);
        }
    }
#undef STAGE
}

extern "C" void kernel_launch(void* const* d_in, const int* in_sizes, int n_in,
                              void* d_out, int out_size, void* d_ws, size_t ws_size,
                              hipStream_t stream) {
    (void)in_sizes; (void)n_in; (void)out_size; (void)ws_size;
    const float* x     = (const float*)d_in[0];
    const float* wqkv  = (const float*)d_in[1];
    const float* wproj = (const float*)d_in[2];
    char* ws = (char*)d_ws;

    bf16_t* xb  = (bf16_t*)(ws);
    bf16_t* wqT = (bf16_t*)(ws + 16777216ull);
    bf16_t* wpT = (bf16_t*)(ws + 23068672ull);
    bf16_t* qb  = (bf16_t*)(ws + 25165824ull);
    bf16_t* kb  = (bf16_t*)(ws + 41943040ull);
    bf16_t* vb  = (bf16_t*)(ws + 58720256ull);
    bf16_t* ob  = (bf16_t*)(ws + 75497472ull);
    float*  cosT = (float*)(ws + 92274688ull);
    float*  sinT = (float*)(ws + 92536832ull);

    k_cvt<<<8192, 256, 0, stream>>>(x, xb, 2097152);
    k_tconv<<<dim3(48, 16), 256, 0, stream>>>(wqkv, wqT, 1024, 3072);
    k_tconv<<<dim3(16, 16), 256, 0, stream>>>(wproj, wpT, 1024, 1024);
    k_tab<<<256, 256, 0, stream>>>(cosT, sinT);
    k_gemm_qkv<<<1536, 256, 0, stream>>>(xb, wqT, cosT, sinT, qb, kb, vb);
    k_attn<<<1024, 256, 0, stream>>>(qb, kb, vb, ob);
    k_gemm_out<<<512, 256, 0, stream>>>(ob, wpT, (float*)d_out);
}